// Round 1
// baseline (1449.792 us; speedup 1.0000x reference)
//
#include <hip/hip_runtime.h>
#include <hip/hip_fp16.h>

typedef _Float16 half8 __attribute__((ext_vector_type(8)));
typedef float floatx4 __attribute__((ext_vector_type(4)));

#define GLL16(g, l)                                                            \
  __builtin_amdgcn_global_load_lds(                                            \
      (const __attribute__((address_space(1))) void*)(g),                      \
      (__attribute__((address_space(3))) void*)(l), 16, 0, 0)

// ---------------------------------------------------------------------------
// Kernel 0a: transpose + split x [b=16, c=512, s=2048] f32 -> xh/xl [row=b*2048+s][c] f16
// ---------------------------------------------------------------------------
__global__ void tsplit_x(const float* __restrict__ x, _Float16* __restrict__ xh,
                         _Float16* __restrict__ xl) {
  __shared__ float tile[32][33];
  const int s0 = blockIdx.x * 32;
  const int c0 = blockIdx.y * 32;
  const int b = blockIdx.z;
  const int tx = threadIdx.x, ty = threadIdx.y;
  const float* src = x + ((size_t)b * 512 + c0) * 2048 + s0;
#pragma unroll
  for (int i = ty; i < 32; i += 8) tile[i][tx] = src[(size_t)i * 2048 + tx];
  __syncthreads();
#pragma unroll
  for (int j = ty; j < 32; j += 8) {
    const int row = b * 2048 + s0 + j;
    float v = tile[tx][j];
    _Float16 h = (_Float16)v;
    float r = v - (float)h;
    _Float16 lo = (_Float16)r;
    xh[(size_t)row * 512 + c0 + tx] = h;
    xl[(size_t)row * 512 + c0 + tx] = lo;
  }
}

// ---------------------------------------------------------------------------
// Kernel 0b: transpose + split centroids [c=512, n=8192] f32 -> cth/ctl [n][c] f16
// ---------------------------------------------------------------------------
__global__ void tsplit_c(const float* __restrict__ c, _Float16* __restrict__ cth,
                         _Float16* __restrict__ ctl) {
  __shared__ float tile[32][33];
  const int n0 = blockIdx.x * 32;
  const int c0 = blockIdx.y * 32;
  const int tx = threadIdx.x, ty = threadIdx.y;
#pragma unroll
  for (int i = ty; i < 32; i += 8) tile[i][tx] = c[(size_t)(c0 + i) * 8192 + n0 + tx];
  __syncthreads();
#pragma unroll
  for (int j = ty; j < 32; j += 8) {
    float v = tile[tx][j];
    _Float16 h = (_Float16)v;
    float r = v - (float)h;
    _Float16 lo = (_Float16)r;
    cth[(size_t)(n0 + j) * 512 + c0 + tx] = h;
    ctl[(size_t)(n0 + j) * 512 + c0 + tx] = lo;
  }
}

// ---------------------------------------------------------------------------
// Kernel 0c: c_sq[n] = sum_c C[c][n]^2   (fp32)
// ---------------------------------------------------------------------------
__global__ void csq_kernel(const float* __restrict__ c, float* __restrict__ csq) {
  __shared__ float red[256];
  const int t = threadIdx.x;
  const int nl = t & 63;
  const int cs = t >> 6;  // 0..3
  const int n = blockIdx.x * 64 + nl;
  float acc = 0.f;
  for (int cc = cs; cc < 512; cc += 4) {
    float v = c[(size_t)cc * 8192 + n];
    acc = fmaf(v, v, acc);
  }
  red[t] = acc;
  __syncthreads();
  if (t < 64) csq[n] = red[t] + red[t + 64] + red[t + 128] + red[t + 192];
}

// ---------------------------------------------------------------------------
// Kernel 1: main GEMM + partial argmin.
//   M_TILE=128, N_TILE=128, BK=32, mfma_f32_16x16x32_f16, 3-product f16 split.
//   Block = 256 threads = 4 waves in 2x2 (wm, wn); wave tile 64x64 = 4x4 frags.
//   LDS per buffer: A_hi/A_lo/B_hi/B_lo each 512 chunks * 16B = 8 KiB (32 KiB/buf).
//   Chunk index = quad*128 + rowlocal; staged via global_load_lds dwordx4.
// ---------------------------------------------------------------------------
__launch_bounds__(256, 2)
__global__ void gemm_argmin(const _Float16* __restrict__ xh, const _Float16* __restrict__ xl,
                            const _Float16* __restrict__ cth, const _Float16* __restrict__ ctl,
                            const float* __restrict__ csq, float* __restrict__ pval,
                            int* __restrict__ pidx) {
  __shared__ __align__(16) unsigned char smem[65536];
  __shared__ float ep_val[256];
  __shared__ int ep_idx[256];

  const int t = threadIdx.x;
  const int m0 = blockIdx.x * 128;
  const int n0 = blockIdx.y * 128;

  // ---- staging setup: thread t owns chunks t (quad=t>>7) and t+256 (quad=t>>7 + 2)
  const int sm = t & 127;   // row-local within tile
  const int sq = t >> 7;    // 0..1
  const _Float16* gAh = xh + (size_t)(m0 + sm) * 512 + sq * 8;
  const _Float16* gAl = xl + (size_t)(m0 + sm) * 512 + sq * 8;
  const _Float16* gBh = cth + (size_t)(n0 + sm) * 512 + sq * 8;
  const _Float16* gBl = ctl + (size_t)(n0 + sm) * 512 + sq * 8;
  const unsigned lo1 = t * 16;          // LDS byte offset of chunk t
  const unsigned lo2 = (t + 256) * 16;  // LDS byte offset of chunk t+256

  auto stage = [&](int buf, int k0) {
    unsigned base = (unsigned)buf * 32768u;
    GLL16(gAh + k0, smem + base + lo1);
    GLL16(gAh + k0 + 16, smem + base + lo2);
    GLL16(gAl + k0, smem + base + 8192 + lo1);
    GLL16(gAl + k0 + 16, smem + base + 8192 + lo2);
    GLL16(gBh + k0, smem + base + 16384 + lo1);
    GLL16(gBh + k0 + 16, smem + base + 16384 + lo2);
    GLL16(gBl + k0, smem + base + 24576 + lo1);
    GLL16(gBl + k0 + 16, smem + base + 24576 + lo2);
  };

  // ---- compute setup
  const int l = t & 63;
  const int w = t >> 6;
  const int wm = w >> 1, wn = w & 1;
  const int l15 = l & 15, lq = l >> 4;  // quad 0..3

  const unsigned caBase = (unsigned)(lq * 128 + wm * 64 + l15);  // + mf*16
  const unsigned cbBase = (unsigned)(lq * 128 + wn * 64 + l15);  // + nf*16

  floatx4 acc[4][4] = {};

  int buf = 0;
  stage(0, 0);
  for (int kc = 0; kc < 16; ++kc) {
    __syncthreads();  // drains vmcnt: current buffer ready; prev compute done
    if (kc < 15) stage(buf ^ 1, (kc + 1) * 32);

    const half8* A_hi = (const half8*)(smem + buf * 32768);
    const half8* A_lo = (const half8*)(smem + buf * 32768 + 8192);
    const half8* B_hi = (const half8*)(smem + buf * 32768 + 16384);
    const half8* B_lo = (const half8*)(smem + buf * 32768 + 24576);

    half8 ah[4], al[4], bh[4], bl[4];
#pragma unroll
    for (int f = 0; f < 4; ++f) {
      ah[f] = A_hi[caBase + f * 16];
      al[f] = A_lo[caBase + f * 16];
      bh[f] = B_hi[cbBase + f * 16];
      bl[f] = B_lo[cbBase + f * 16];
    }
    // 3 products, interleaved so each accumulator's chain distance is 16
#pragma unroll
    for (int mf = 0; mf < 4; ++mf)
#pragma unroll
      for (int nf = 0; nf < 4; ++nf)
        acc[mf][nf] = __builtin_amdgcn_mfma_f32_16x16x32_f16(ah[mf], bh[nf], acc[mf][nf], 0, 0, 0);
#pragma unroll
    for (int mf = 0; mf < 4; ++mf)
#pragma unroll
      for (int nf = 0; nf < 4; ++nf)
        acc[mf][nf] = __builtin_amdgcn_mfma_f32_16x16x32_f16(ah[mf], bl[nf], acc[mf][nf], 0, 0, 0);
#pragma unroll
    for (int mf = 0; mf < 4; ++mf)
#pragma unroll
      for (int nf = 0; nf < 4; ++nf)
        acc[mf][nf] = __builtin_amdgcn_mfma_f32_16x16x32_f16(al[mf], bh[nf], acc[mf][nf], 0, 0, 0);
    buf ^= 1;
  }

  // ---- epilogue: score = c_sq[n] - 2*dot; argmin over this block's 128 cols
  float cs[4];
#pragma unroll
  for (int nf = 0; nf < 4; ++nf) cs[nf] = csq[n0 + wn * 64 + nf * 16 + l15];

#pragma unroll
  for (int mf = 0; mf < 4; ++mf) {
#pragma unroll
    for (int reg = 0; reg < 4; ++reg) {
      float v = INFINITY;
      int idx = 0;
#pragma unroll
      for (int nf = 0; nf < 4; ++nf) {
        float sv = fmaf(-2.f, acc[mf][nf][reg], cs[nf]);
        int si = n0 + wn * 64 + nf * 16 + l15;
        if (sv < v || (sv == v && si < idx)) { v = sv; idx = si; }
      }
      // butterfly across the 16 columns (lanes sharing lq)
#pragma unroll
      for (int off = 8; off >= 1; off >>= 1) {
        float ov = __shfl_xor(v, off, 64);
        int oi = __shfl_xor(idx, off, 64);
        if (ov < v || (ov == v && oi < idx)) { v = ov; idx = oi; }
      }
      if (l15 == 0) {
        int row_local = wm * 64 + mf * 16 + lq * 4 + reg;
        ep_val[row_local * 2 + wn] = v;
        ep_idx[row_local * 2 + wn] = idx;
      }
    }
  }
  __syncthreads();
  if (t < 128) {
    float v0 = ep_val[t * 2], v1 = ep_val[t * 2 + 1];
    int i0 = ep_idx[t * 2], i1 = ep_idx[t * 2 + 1];
    bool take1 = (v1 < v0) || (v1 == v0 && i1 < i0);
    float v = take1 ? v1 : v0;
    int i = take1 ? i1 : i0;
    pval[(size_t)blockIdx.y * 32768 + m0 + t] = v;
    pidx[(size_t)blockIdx.y * 32768 + m0 + t] = i;
  }
}

// ---------------------------------------------------------------------------
// Kernel 2: reduce partial argmins over 64 n-blocks
// ---------------------------------------------------------------------------
__global__ void final_argmin(const float* __restrict__ pval, const int* __restrict__ pidx,
                             int* __restrict__ out) {
  const int row = blockIdx.x * 256 + threadIdx.x;
  float bv = INFINITY;
  int bi = 0;
  for (int nb = 0; nb < 64; ++nb) {
    float v = pval[(size_t)nb * 32768 + row];
    int i = pidx[(size_t)nb * 32768 + row];
    if (v < bv || (v == bv && i < bi)) { bv = v; bi = i; }
  }
  out[row] = bi;
}

// ---------------------------------------------------------------------------
// Fallback (only if ws too small): exact distances, slow but correct.
// ---------------------------------------------------------------------------
__global__ void fallback_kernel(const float* __restrict__ x, const float* __restrict__ cen,
                                int* __restrict__ out) {
  __shared__ float xrow[512];
  __shared__ float rv[256];
  __shared__ int ri[256];
  const int row = blockIdx.x;
  const int b = row >> 11, s = row & 2047;
  const int t = threadIdx.x;
  for (int c = t; c < 512; c += 256) xrow[c] = x[((size_t)b * 512 + c) * 2048 + s];
  __syncthreads();
  float bv = INFINITY;
  int bi = 0;
  for (int k = t; k < 8192; k += 256) {
    float d = 0.f;
    for (int c = 0; c < 512; ++c) {
      float diff = xrow[c] - cen[(size_t)c * 8192 + k];
      d = fmaf(diff, diff, d);
    }
    if (d < bv) { bv = d; bi = k; }
  }
  rv[t] = bv;
  ri[t] = bi;
  __syncthreads();
  for (int off = 128; off > 0; off >>= 1) {
    if (t < off) {
      if (rv[t + off] < rv[t] || (rv[t + off] == rv[t] && ri[t + off] < ri[t])) {
        rv[t] = rv[t + off];
        ri[t] = ri[t + off];
      }
    }
    __syncthreads();
  }
  if (t == 0) out[row] = ri[0];
}

// ---------------------------------------------------------------------------
extern "C" void kernel_launch(void* const* d_in, const int* in_sizes, int n_in,
                              void* d_out, int out_size, void* d_ws, size_t ws_size,
                              hipStream_t stream) {
  const float* x = (const float*)d_in[0];     // [16, 512, 2048]
  const float* cen = (const float*)d_in[1];   // [512, 8192]
  int* out = (int*)d_out;                     // [16*2048] int32 labels

  const size_t XSZ = (size_t)32768 * 512;  // halfs
  const size_t CSZ = (size_t)8192 * 512;   // halfs
  const size_t NEED = XSZ * 2 * 2 + CSZ * 2 * 2 + 8192 * 4 + (size_t)64 * 32768 * 8;

  if (ws_size < NEED) {
    fallback_kernel<<<32768, 256, 0, stream>>>(x, cen, out);
    return;
  }

  char* ws = (char*)d_ws;
  _Float16* xh = (_Float16*)ws;
  _Float16* xl = xh + XSZ;
  _Float16* cth = xl + XSZ;
  _Float16* ctl = cth + CSZ;
  float* csq = (float*)(ctl + CSZ);
  float* pv = csq + 8192;
  int* pi = (int*)(pv + (size_t)64 * 32768);

  tsplit_x<<<dim3(64, 16, 16), dim3(32, 8), 0, stream>>>(x, xh, xl);
  tsplit_c<<<dim3(256, 16), dim3(32, 8), 0, stream>>>(cen, cth, ctl);
  csq_kernel<<<128, 256, 0, stream>>>(cen, csq);
  gemm_argmin<<<dim3(256, 64), 256, 0, stream>>>(xh, xl, cth, ctl, csq, pv, pi);
  final_argmin<<<128, 256, 0, stream>>>(pv, pi, out);
}

// Round 2
// 1300.169 us; speedup vs baseline: 1.1151x; 1.1151x over previous
//
#include <hip/hip_runtime.h>
#include <hip/hip_fp16.h>

typedef _Float16 half8 __attribute__((ext_vector_type(8)));
typedef float floatx4 __attribute__((ext_vector_type(4)));

#define GLL16(g, l)                                                            \
  __builtin_amdgcn_global_load_lds(                                            \
      (const __attribute__((address_space(1))) void*)(g),                      \
      (__attribute__((address_space(3))) void*)(l), 16, 0, 0)

// ---------------------------------------------------------------------------
// Kernel 0a: transpose + split x [b=16, c=512, s=2048] f32 -> xh/xl [row=b*2048+s][c] f16
// ---------------------------------------------------------------------------
__global__ void tsplit_x(const float* __restrict__ x, _Float16* __restrict__ xh,
                         _Float16* __restrict__ xl) {
  __shared__ float tile[32][33];
  const int s0 = blockIdx.x * 32;
  const int c0 = blockIdx.y * 32;
  const int b = blockIdx.z;
  const int tx = threadIdx.x, ty = threadIdx.y;
  const float* src = x + ((size_t)b * 512 + c0) * 2048 + s0;
#pragma unroll
  for (int i = ty; i < 32; i += 8) tile[i][tx] = src[(size_t)i * 2048 + tx];
  __syncthreads();
#pragma unroll
  for (int j = ty; j < 32; j += 8) {
    const int row = b * 2048 + s0 + j;
    float v = tile[tx][j];
    _Float16 h = (_Float16)v;
    float r = v - (float)h;
    _Float16 lo = (_Float16)r;
    xh[(size_t)row * 512 + c0 + tx] = h;
    xl[(size_t)row * 512 + c0 + tx] = lo;
  }
}

// ---------------------------------------------------------------------------
// Kernel 0b: transpose + split centroids [c=512, n=8192] f32 -> cth/ctl [n][c] f16
// ---------------------------------------------------------------------------
__global__ void tsplit_c(const float* __restrict__ c, _Float16* __restrict__ cth,
                         _Float16* __restrict__ ctl) {
  __shared__ float tile[32][33];
  const int n0 = blockIdx.x * 32;
  const int c0 = blockIdx.y * 32;
  const int tx = threadIdx.x, ty = threadIdx.y;
#pragma unroll
  for (int i = ty; i < 32; i += 8) tile[i][tx] = c[(size_t)(c0 + i) * 8192 + n0 + tx];
  __syncthreads();
#pragma unroll
  for (int j = ty; j < 32; j += 8) {
    float v = tile[tx][j];
    _Float16 h = (_Float16)v;
    float r = v - (float)h;
    _Float16 lo = (_Float16)r;
    cth[(size_t)(n0 + j) * 512 + c0 + tx] = h;
    ctl[(size_t)(n0 + j) * 512 + c0 + tx] = lo;
  }
}

// ---------------------------------------------------------------------------
// Kernel 0c: c_sq[n] = sum_c C[c][n]^2   (fp32)
// ---------------------------------------------------------------------------
__global__ void csq_kernel(const float* __restrict__ c, float* __restrict__ csq) {
  __shared__ float red[256];
  const int t = threadIdx.x;
  const int nl = t & 63;
  const int cs = t >> 6;  // 0..3
  const int n = blockIdx.x * 64 + nl;
  float acc = 0.f;
  for (int cc = cs; cc < 512; cc += 4) {
    float v = c[(size_t)cc * 8192 + n];
    acc = fmaf(v, v, acc);
  }
  red[t] = acc;
  __syncthreads();
  if (t < 64) csq[n] = red[t] + red[t + 64] + red[t + 128] + red[t + 192];
}

// ---------------------------------------------------------------------------
// Kernel 1: main GEMM + partial argmin.
//   M_TILE=128, N_TILE=128, BK=32, mfma_f32_16x16x32_f16, 3-product f16 split.
//   SINGLE-buffered LDS (m97-proven shape): 32 KiB staging + ~3 KiB epilogue
//   -> 4 blocks/CU (vs 2 with dbuf). Cross-block wave overlap hides the
//   stage->barrier vmcnt drain (m99/m100: explicit dbuf is neutral anyway).
// ---------------------------------------------------------------------------
__launch_bounds__(256, 4)
__global__ void gemm_argmin(const _Float16* __restrict__ xh, const _Float16* __restrict__ xl,
                            const _Float16* __restrict__ cth, const _Float16* __restrict__ ctl,
                            const float* __restrict__ csq, float* __restrict__ pval,
                            int* __restrict__ pidx) {
  __shared__ __align__(16) unsigned char smem[32768];
  __shared__ float ep_val[256];
  __shared__ int ep_idx[256];

  const int t = threadIdx.x;
  const int m0 = blockIdx.x * 128;
  const int n0 = blockIdx.y * 128;

  // ---- staging setup: thread t owns chunks t (quad=t>>7) and t+256 (quad=t>>7 + 2)
  const int sm = t & 127;   // row-local within tile
  const int sq = t >> 7;    // 0..1
  const _Float16* gAh = xh + (size_t)(m0 + sm) * 512 + sq * 8;
  const _Float16* gAl = xl + (size_t)(m0 + sm) * 512 + sq * 8;
  const _Float16* gBh = cth + (size_t)(n0 + sm) * 512 + sq * 8;
  const _Float16* gBl = ctl + (size_t)(n0 + sm) * 512 + sq * 8;
  const unsigned lo1 = t * 16;          // LDS byte offset of chunk t
  const unsigned lo2 = (t + 256) * 16;  // LDS byte offset of chunk t+256

  auto stage = [&](int k0) {
    GLL16(gAh + k0, smem + lo1);
    GLL16(gAh + k0 + 16, smem + lo2);
    GLL16(gAl + k0, smem + 8192 + lo1);
    GLL16(gAl + k0 + 16, smem + 8192 + lo2);
    GLL16(gBh + k0, smem + 16384 + lo1);
    GLL16(gBh + k0 + 16, smem + 16384 + lo2);
    GLL16(gBl + k0, smem + 24576 + lo1);
    GLL16(gBl + k0 + 16, smem + 24576 + lo2);
  };

  // ---- compute setup
  const int l = t & 63;
  const int w = t >> 6;
  const int wm = w >> 1, wn = w & 1;
  const int l15 = l & 15, lq = l >> 4;  // quad 0..3

  const unsigned caBase = (unsigned)(lq * 128 + wm * 64 + l15);  // + mf*16
  const unsigned cbBase = (unsigned)(lq * 128 + wn * 64 + l15);  // + nf*16

  floatx4 acc[4][4] = {};

  const half8* A_hi = (const half8*)(smem);
  const half8* A_lo = (const half8*)(smem + 8192);
  const half8* B_hi = (const half8*)(smem + 16384);
  const half8* B_lo = (const half8*)(smem + 24576);

  for (int kc = 0; kc < 16; ++kc) {
    stage(kc * 32);
    __syncthreads();  // vmcnt(0) drain: buffer ready for all threads

    half8 ah[4], al[4], bh[4], bl[4];
#pragma unroll
    for (int f = 0; f < 4; ++f) {
      ah[f] = A_hi[caBase + f * 16];
      al[f] = A_lo[caBase + f * 16];
      bh[f] = B_hi[cbBase + f * 16];
      bl[f] = B_lo[cbBase + f * 16];
    }
    // 3 products, interleaved so each accumulator's chain distance is 16
#pragma unroll
    for (int mf = 0; mf < 4; ++mf)
#pragma unroll
      for (int nf = 0; nf < 4; ++nf)
        acc[mf][nf] = __builtin_amdgcn_mfma_f32_16x16x32_f16(ah[mf], bh[nf], acc[mf][nf], 0, 0, 0);
#pragma unroll
    for (int mf = 0; mf < 4; ++mf)
#pragma unroll
      for (int nf = 0; nf < 4; ++nf)
        acc[mf][nf] = __builtin_amdgcn_mfma_f32_16x16x32_f16(ah[mf], bl[nf], acc[mf][nf], 0, 0, 0);
#pragma unroll
    for (int mf = 0; mf < 4; ++mf)
#pragma unroll
      for (int nf = 0; nf < 4; ++nf)
        acc[mf][nf] = __builtin_amdgcn_mfma_f32_16x16x32_f16(al[mf], bh[nf], acc[mf][nf], 0, 0, 0);

    __syncthreads();  // all ds_reads done before next stage overwrites
  }

  // ---- epilogue: score = c_sq[n] - 2*dot; argmin over this block's 128 cols
  float cs[4];
#pragma unroll
  for (int nf = 0; nf < 4; ++nf) cs[nf] = csq[n0 + wn * 64 + nf * 16 + l15];

#pragma unroll
  for (int mf = 0; mf < 4; ++mf) {
#pragma unroll
    for (int reg = 0; reg < 4; ++reg) {
      float v = INFINITY;
      int idx = 0;
#pragma unroll
      for (int nf = 0; nf < 4; ++nf) {
        float sv = fmaf(-2.f, acc[mf][nf][reg], cs[nf]);
        int si = n0 + wn * 64 + nf * 16 + l15;
        if (sv < v || (sv == v && si < idx)) { v = sv; idx = si; }
      }
      // butterfly across the 16 columns (lanes sharing lq)
#pragma unroll
      for (int off = 8; off >= 1; off >>= 1) {
        float ov = __shfl_xor(v, off, 64);
        int oi = __shfl_xor(idx, off, 64);
        if (ov < v || (ov == v && oi < idx)) { v = ov; idx = oi; }
      }
      if (l15 == 0) {
        int row_local = wm * 64 + mf * 16 + lq * 4 + reg;
        ep_val[row_local * 2 + wn] = v;
        ep_idx[row_local * 2 + wn] = idx;
      }
    }
  }
  __syncthreads();
  if (t < 128) {
    float v0 = ep_val[t * 2], v1 = ep_val[t * 2 + 1];
    int i0 = ep_idx[t * 2], i1 = ep_idx[t * 2 + 1];
    bool take1 = (v1 < v0) || (v1 == v0 && i1 < i0);
    float v = take1 ? v1 : v0;
    int i = take1 ? i1 : i0;
    pval[(size_t)blockIdx.y * 32768 + m0 + t] = v;
    pidx[(size_t)blockIdx.y * 32768 + m0 + t] = i;
  }
}

// ---------------------------------------------------------------------------
// Kernel 2: reduce partial argmins over 64 n-blocks
// ---------------------------------------------------------------------------
__global__ void final_argmin(const float* __restrict__ pval, const int* __restrict__ pidx,
                             int* __restrict__ out) {
  const int row = blockIdx.x * 256 + threadIdx.x;
  float bv = INFINITY;
  int bi = 0;
  for (int nb = 0; nb < 64; ++nb) {
    float v = pval[(size_t)nb * 32768 + row];
    int i = pidx[(size_t)nb * 32768 + row];
    if (v < bv || (v == bv && i < bi)) { bv = v; bi = i; }
  }
  out[row] = bi;
}

// ---------------------------------------------------------------------------
// Fallback (only if ws too small): exact distances, slow but correct.
// ---------------------------------------------------------------------------
__global__ void fallback_kernel(const float* __restrict__ x, const float* __restrict__ cen,
                                int* __restrict__ out) {
  __shared__ float xrow[512];
  __shared__ float rv[256];
  __shared__ int ri[256];
  const int row = blockIdx.x;
  const int b = row >> 11, s = row & 2047;
  const int t = threadIdx.x;
  for (int c = t; c < 512; c += 256) xrow[c] = x[((size_t)b * 512 + c) * 2048 + s];
  __syncthreads();
  float bv = INFINITY;
  int bi = 0;
  for (int k = t; k < 8192; k += 256) {
    float d = 0.f;
    for (int c = 0; c < 512; ++c) {
      float diff = xrow[c] - cen[(size_t)c * 8192 + k];
      d = fmaf(diff, diff, d);
    }
    if (d < bv) { bv = d; bi = k; }
  }
  rv[t] = bv;
  ri[t] = bi;
  __syncthreads();
  for (int off = 128; off > 0; off >>= 1) {
    if (t < off) {
      if (rv[t + off] < rv[t] || (rv[t + off] == rv[t] && ri[t + off] < ri[t])) {
        rv[t] = rv[t + off];
        ri[t] = ri[t + off];
      }
    }
    __syncthreads();
  }
  if (t == 0) out[row] = ri[0];
}

// ---------------------------------------------------------------------------
extern "C" void kernel_launch(void* const* d_in, const int* in_sizes, int n_in,
                              void* d_out, int out_size, void* d_ws, size_t ws_size,
                              hipStream_t stream) {
  const float* x = (const float*)d_in[0];     // [16, 512, 2048]
  const float* cen = (const float*)d_in[1];   // [512, 8192]
  int* out = (int*)d_out;                     // [16*2048] int32 labels

  const size_t XSZ = (size_t)32768 * 512;  // halfs
  const size_t CSZ = (size_t)8192 * 512;   // halfs
  const size_t NEED = XSZ * 2 * 2 + CSZ * 2 * 2 + 8192 * 4 + (size_t)64 * 32768 * 8;

  if (ws_size < NEED) {
    fallback_kernel<<<32768, 256, 0, stream>>>(x, cen, out);
    return;
  }

  char* ws = (char*)d_ws;
  _Float16* xh = (_Float16*)ws;
  _Float16* xl = xh + XSZ;
  _Float16* cth = xl + XSZ;
  _Float16* ctl = cth + CSZ;
  float* csq = (float*)(ctl + CSZ);
  float* pv = csq + 8192;
  int* pi = (int*)(pv + (size_t)64 * 32768);

  tsplit_x<<<dim3(64, 16, 16), dim3(32, 8), 0, stream>>>(x, xh, xl);
  tsplit_c<<<dim3(256, 16), dim3(32, 8), 0, stream>>>(cen, cth, ctl);
  csq_kernel<<<128, 256, 0, stream>>>(cen, csq);
  gemm_argmin<<<dim3(256, 64), 256, 0, stream>>>(xh, xl, cth, ctl, csq, pv, pi);
  final_argmin<<<128, 256, 0, stream>>>(pv, pi, out);
}